// Round 1
// baseline (10364.640 us; speedup 1.0000x reference)
//
#include <hip/hip_runtime.h>
#include <math.h>

// Problem constants (fixed by the reference).
#define N_ROWS   8192
#define K_CODES  8192
#define H_DIM    256
#define NSPLIT   8
#define KSPLIT   (K_CODES / NSPLIT)   // 1024 codes per k-split
#define MARGIN   6e-3f                // gap below which we re-resolve argmin in fp64

// GEMM-min tiling
#define BM 128
#define BN 128
#define BH 32
#define TM 8
#define TN 8
#define ASTRIDE (BH + 4)              // 36 floats: +4 pad keeps 16B align, breaks bank stride

// Workspace layout (float offsets)
#define C2_OFF      0                         // [8192]  ||c_k||^2
#define H2_OFF      8192                      // [8192]  ||h_n||^2
#define BESTP_OFF   16384                     // [8][8192] per-split best partial (c2 - 2hc)
#define SECONDP_OFF (BESTP_OFF + 8*8192)      // [8][8192]
#define IDXP_OFF    (SECONDP_OFF + 8*8192)    // [8][8192] (int)
#define DISTF_OFF   (IDXP_OFF + 8*8192)       // [8192] full min dist ||h-c||^2
#define IDXF_OFF    (DISTF_OFF + 8192)        // [8192] (int) final argmin
#define GAP_OFF     (IDXF_OFF + 8192)         // [8192] second - best (partial)

// ---------------------------------------------------------------------------
// P: per-vector squared norms. Blocks 0..2047 -> codebook, 2048..4095 -> h.
// One wave per vector: 64 lanes x float4 = 256 floats.
__global__ __launch_bounds__(256) void prep_sq(const float* __restrict__ h,
                                               const float* __restrict__ cb,
                                               float* __restrict__ ws) {
    int blk  = blockIdx.x;
    int wave = threadIdx.x >> 6;
    int lane = threadIdx.x & 63;
    bool isH = blk >= 2048;
    int idx  = (isH ? (blk - 2048) : blk) * 4 + wave;
    const float* src = isH ? h : cb;
    const float4* p = (const float4*)(src + (size_t)idx * H_DIM);
    float4 v = p[lane];
    float s = v.x*v.x + v.y*v.y + v.z*v.z + v.w*v.w;
    #pragma unroll
    for (int off = 32; off > 0; off >>= 1) s += __shfl_down(s, off, 64);
    if (lane == 0) ws[(isH ? H2_OFF : C2_OFF) + idx] = s;
}

// ---------------------------------------------------------------------------
// A: fp32 GEMM-min. Block = (row-tile, k-split). 256 threads, 8x8 per thread.
// Tracks per-row best/second/argmin of partial dist d = ||c||^2 - 2 h.c
__global__ __launch_bounds__(256, 2) void vq_min_kernel(const float* __restrict__ h,
                                                        const float* __restrict__ cb,
                                                        float* __restrict__ ws) {
    __shared__ float smem[2 * BM * ASTRIDE];   // As | Bs (reused for epilogue merge)
    __shared__ float c2s[BN];
    float (*As)[ASTRIDE] = (float (*)[ASTRIDE])smem;
    float (*Bs)[ASTRIDE] = (float (*)[ASTRIDE])(smem + BM * ASTRIDE);

    const int row0 = blockIdx.x * BM;
    const int k0   = blockIdx.y * KSPLIT;
    const int tid  = threadIdx.x;
    const int tr   = tid >> 4;     // 0..15
    const int tc   = tid & 15;     // 0..15

    float best[TM], second[TM];
    int   bidx[TM];
    #pragma unroll
    for (int i = 0; i < TM; i++) { best[i] = 3.4e38f; second[i] = 3.4e38f; bidx[i] = 0; }

    const float* c2g = ws + C2_OFF;

    for (int kt = 0; kt < KSPLIT; kt += BN) {
        const int kbase = k0 + kt;
        float dot[TM][TN];
        #pragma unroll
        for (int i = 0; i < TM; i++)
            #pragma unroll
            for (int j = 0; j < TN; j++) dot[i][j] = 0.f;

        __syncthreads();                      // protect c2s/smem from previous iter readers
        if (tid < BN) c2s[tid] = c2g[kbase + tid];

        for (int hc = 0; hc < H_DIM; hc += BH) {
            __syncthreads();
            // stage A tile (128 rows x 32 h) and B tile (128 codes x 32 h)
            #pragma unroll
            for (int i = 0; i < 4; i++) {
                int f  = tid + 256 * i;       // 0..1023
                int r  = f >> 3;
                int c4 = f & 7;
                float4 va = *(const float4*)(h  + (size_t)(row0 + r) * H_DIM + hc + c4 * 4);
                *(float4*)&As[r][c4 * 4] = va;
                float4 vb = *(const float4*)(cb + (size_t)(kbase + r) * H_DIM + hc + c4 * 4);
                *(float4*)&Bs[r][c4 * 4] = vb;
            }
            __syncthreads();
            #pragma unroll
            for (int h4 = 0; h4 < BH / 4; h4++) {
                float4 a[TM], b[TN];
                #pragma unroll
                for (int i = 0; i < TM; i++) a[i] = *(const float4*)&As[tr + 16 * i][h4 * 4];
                #pragma unroll
                for (int j = 0; j < TN; j++) b[j] = *(const float4*)&Bs[tc + 16 * j][h4 * 4];
                #pragma unroll
                for (int i = 0; i < TM; i++)
                    #pragma unroll
                    for (int j = 0; j < TN; j++)
                        dot[i][j] += a[i].x * b[j].x + a[i].y * b[j].y
                                   + a[i].z * b[j].z + a[i].w * b[j].w;
            }
        }
        // distances + tracker update (j ascending => k ascending within thread)
        #pragma unroll
        for (int j = 0; j < TN; j++) {
            int col = tc + 16 * j;
            int k   = kbase + col;
            float c2v = c2s[col];
            #pragma unroll
            for (int i = 0; i < TM; i++) {
                float d = c2v - 2.f * dot[i][j];
                if (d < best[i])        { second[i] = best[i]; best[i] = d; bidx[i] = k; }
                else if (d < second[i]) { second[i] = d; }
            }
        }
    }

    // Epilogue: merge the 16 thread-columns per row via LDS (overlay on smem).
    __syncthreads();
    float* mbest   = smem;
    float* msecond = smem + BM * 16;
    int*   midx    = (int*)(smem + 2 * BM * 16);
    #pragma unroll
    for (int i = 0; i < TM; i++) {
        int r = tr + 16 * i;
        mbest[r * 16 + tc]   = best[i];
        msecond[r * 16 + tc] = second[i];
        midx[r * 16 + tc]    = bidx[i];
    }
    __syncthreads();
    if (tid < BM) {
        float b  = mbest[tid * 16];
        float s2 = msecond[tid * 16];
        int   bi = midx[tid * 16];
        for (int t = 1; t < 16; t++) {
            float ob = mbest[tid * 16 + t];
            float os = msecond[tid * 16 + t];
            int   oi = midx[tid * 16 + t];
            if (ob < b)       { s2 = fminf(b, os); b = ob; bi = oi; }
            else if (ob > b)  { s2 = fminf(s2, ob); }
            else              { if (oi < bi) bi = oi; s2 = b; }
        }
        int row = row0 + tid;
        int s   = blockIdx.y;
        ws[BESTP_OFF   + s * N_ROWS + row] = b;
        ws[SECONDP_OFF + s * N_ROWS + row] = s2;
        ((int*)ws)[IDXP_OFF + s * N_ROWS + row] = bi;
    }
}

// ---------------------------------------------------------------------------
// M: merge the 8 k-splits per row; emit full dist, argmin, and tie gap.
__global__ __launch_bounds__(256) void merge_kernel(float* __restrict__ ws) {
    int row = blockIdx.x * blockDim.x + threadIdx.x;
    if (row >= N_ROWS) return;
    float b  = ws[BESTP_OFF + row];
    float s2 = ws[SECONDP_OFF + row];
    int   bi = ((int*)ws)[IDXP_OFF + row];
    for (int s = 1; s < NSPLIT; s++) {
        float ob = ws[BESTP_OFF   + s * N_ROWS + row];
        float os = ws[SECONDP_OFF + s * N_ROWS + row];
        int   oi = ((int*)ws)[IDXP_OFF + s * N_ROWS + row];
        if (ob < b)      { s2 = fminf(b, os); b = ob; bi = oi; }
        else if (ob > b) { s2 = fminf(s2, ob); }
        else             { if (oi < bi) bi = oi; s2 = b; }
    }
    float h2 = ws[H2_OFF + row];
    ws[DISTF_OFF + row] = h2 + b;       // ||h - c||^2 at the argmin
    ((int*)ws)[IDXF_OFF + row] = bi;
    ws[GAP_OFF + row] = s2 - b;
}

// ---------------------------------------------------------------------------
// C: fp64 re-resolution for near-tie rows (gap <= MARGIN). One block per row;
// non-flagged blocks exit immediately.
__global__ __launch_bounds__(256) void fixup_kernel(const float* __restrict__ h,
                                                    const float* __restrict__ cb,
                                                    float* __restrict__ ws) {
    int row = blockIdx.x;
    if (ws[GAP_OFF + row] > MARGIN) return;

    __shared__ float hrow[H_DIM];
    __shared__ double sb[256];
    __shared__ int    si[256];
    int tid = threadIdx.x;
    hrow[tid] = h[(size_t)row * H_DIM + tid];
    __syncthreads();

    double bestd = 1e300;
    int    bi    = K_CODES;
    for (int k = tid; k < K_CODES; k += 256) {   // k ascending per thread
        const float* c = cb + (size_t)k * H_DIM;
        double acc = 0.0;
        for (int x = 0; x < H_DIM; x++) {
            double d = (double)hrow[x] - (double)c[x];
            acc += d * d;
        }
        if (acc < bestd) { bestd = acc; bi = k; }
    }
    sb[tid] = bestd; si[tid] = bi;
    __syncthreads();
    for (int off = 128; off > 0; off >>= 1) {
        if (tid < off) {
            double ob = sb[tid + off]; int oi = si[tid + off];
            if (ob < sb[tid] || (ob == sb[tid] && oi < si[tid])) { sb[tid] = ob; si[tid] = oi; }
        }
        __syncthreads();
    }
    if (tid == 0) {
        ws[DISTF_OFF + row] = (float)sb[0];
        ((int*)ws)[IDXF_OFF + row] = si[0];
    }
}

// ---------------------------------------------------------------------------
// B: write one-hot rows (float4 streaming stores) + loss.
__global__ __launch_bounds__(256) void writeout_kernel(const float* __restrict__ ws,
                                                       float* __restrict__ out) {
    int row = blockIdx.x;
    int tid = threadIdx.x;
    int bi  = ((const int*)ws)[IDXF_OFF + row];
    float4* orow = (float4*)(out + (size_t)row * K_CODES);
    #pragma unroll
    for (int i = 0; i < 8; i++) {
        int f4 = tid + 256 * i;            // 0..2047
        float4 v = make_float4(0.f, 0.f, 0.f, 0.f);
        if ((bi >> 2) == f4) ((float*)&v)[bi & 3] = 1.0f;
        orow[f4] = v;
    }
    if (tid == 0) {
        out[(size_t)N_ROWS * K_CODES + row] = (1.25f / 256.f) * ws[DISTF_OFF + row];
    }
}

// ---------------------------------------------------------------------------
extern "C" void kernel_launch(void* const* d_in, const int* in_sizes, int n_in,
                              void* d_out, int out_size, void* d_ws, size_t ws_size,
                              hipStream_t stream) {
    const float* h  = (const float*)d_in[0];
    // d_in[1] = temperature (unused)
    const float* cb = (const float*)d_in[2];
    float* out = (float*)d_out;
    float* ws  = (float*)d_ws;

    prep_sq<<<4096, 256, 0, stream>>>(h, cb, ws);
    vq_min_kernel<<<dim3(N_ROWS / BM, NSPLIT), 256, 0, stream>>>(h, cb, ws);
    merge_kernel<<<N_ROWS / 256, 256, 0, stream>>>(ws);
    fixup_kernel<<<N_ROWS, 256, 0, stream>>>(h, cb, ws);
    writeout_kernel<<<N_ROWS, 256, 0, stream>>>(ws, out);
}

// Round 2
// 4009.189 us; speedup vs baseline: 2.5852x; 2.5852x over previous
//
#include <hip/hip_runtime.h>
#include <math.h>

// Problem constants (fixed by the reference).
#define N_ROWS   8192
#define K_CODES  8192
#define H_DIM    256
#define NSPLIT   8
#define KSPLIT   (K_CODES / NSPLIT)   // 1024 codes per k-split
#define MARGIN   6e-3f                // gap below which we re-resolve argmin in fp64

// GEMM-min tiling
#define BM 128
#define BN 128
#define BH 32
#define TM 8
#define TN 8
#define ASTRIDE (BH + 4)              // 36 floats: +4 pad keeps 16B align, breaks bank stride

// Workspace layout (float offsets)
#define C2_OFF      0                         // [8192]  ||c_k||^2
#define H2_OFF      8192                      // [8192]  ||h_n||^2
#define BESTP_OFF   16384                     // [8][8192] per-split best partial (c2 - 2hc)
#define SECONDP_OFF (BESTP_OFF + 8*8192)      // [8][8192]
#define IDXP_OFF    (SECONDP_OFF + 8*8192)    // [8][8192] (int)
#define DISTF_OFF   (IDXP_OFF + 8*8192)       // [8192] full min dist ||h-c||^2
#define IDXF_OFF    (DISTF_OFF + 8192)        // [8192] (int) final argmin
#define GAP_OFF     (IDXF_OFF + 8192)         // [8192] second - best (partial)

// ---------------------------------------------------------------------------
// P: per-vector squared norms. Blocks 0..2047 -> codebook, 2048..4095 -> h.
// One wave per vector: 64 lanes x float4 = 256 floats.
__global__ __launch_bounds__(256) void prep_sq(const float* __restrict__ h,
                                               const float* __restrict__ cb,
                                               float* __restrict__ ws) {
    int blk  = blockIdx.x;
    int wave = threadIdx.x >> 6;
    int lane = threadIdx.x & 63;
    bool isH = blk >= 2048;
    int idx  = (isH ? (blk - 2048) : blk) * 4 + wave;
    const float* src = isH ? h : cb;
    const float4* p = (const float4*)(src + (size_t)idx * H_DIM);
    float4 v = p[lane];
    float s = v.x*v.x + v.y*v.y + v.z*v.z + v.w*v.w;
    #pragma unroll
    for (int off = 32; off > 0; off >>= 1) s += __shfl_down(s, off, 64);
    if (lane == 0) ws[(isH ? H2_OFF : C2_OFF) + idx] = s;
}

// ---------------------------------------------------------------------------
// A: fp32 GEMM-min. Block = (row-tile, k-split). 256 threads, 8x8 per thread.
// Tracks per-row best/second/argmin of partial dist d = ||c||^2 - 2 h.c
// NOTE: __launch_bounds__(256, 1) — waves-per-eu min 1 lets the allocator use
// up to 512 VGPRs. With (256,2) the compiler allocated 128 VGPRs and spilled
// ~40 regs in the K-loop -> 18.5 GB scratch WRITE_SIZE, 9.6 ms (R1 post-mortem).
__global__ __launch_bounds__(256, 1) void vq_min_kernel(const float* __restrict__ h,
                                                        const float* __restrict__ cb,
                                                        float* __restrict__ ws) {
    __shared__ float smem[2 * BM * ASTRIDE];   // As | Bs (reused for epilogue merge)
    __shared__ float c2s[BN];
    float (*As)[ASTRIDE] = (float (*)[ASTRIDE])smem;
    float (*Bs)[ASTRIDE] = (float (*)[ASTRIDE])(smem + BM * ASTRIDE);

    const int row0 = blockIdx.x * BM;
    const int k0   = blockIdx.y * KSPLIT;
    const int tid  = threadIdx.x;
    const int tr   = tid >> 4;     // 0..15
    const int tc   = tid & 15;     // 0..15

    float best[TM], second[TM];
    int   bidx[TM];
    #pragma unroll
    for (int i = 0; i < TM; i++) { best[i] = 3.4e38f; second[i] = 3.4e38f; bidx[i] = 0; }

    const float* c2g = ws + C2_OFF;

    for (int kt = 0; kt < KSPLIT; kt += BN) {
        const int kbase = k0 + kt;
        float dot[TM][TN];
        #pragma unroll
        for (int i = 0; i < TM; i++)
            #pragma unroll
            for (int j = 0; j < TN; j++) dot[i][j] = 0.f;

        __syncthreads();                      // protect c2s/smem from previous iter readers
        if (tid < BN) c2s[tid] = c2g[kbase + tid];

        for (int hc = 0; hc < H_DIM; hc += BH) {
            __syncthreads();
            // stage A tile (128 rows x 32 h) and B tile (128 codes x 32 h)
            #pragma unroll
            for (int i = 0; i < 4; i++) {
                int f  = tid + 256 * i;       // 0..1023
                int r  = f >> 3;
                int c4 = f & 7;
                float4 va = *(const float4*)(h  + (size_t)(row0 + r) * H_DIM + hc + c4 * 4);
                *(float4*)&As[r][c4 * 4] = va;
                float4 vb = *(const float4*)(cb + (size_t)(kbase + r) * H_DIM + hc + c4 * 4);
                *(float4*)&Bs[r][c4 * 4] = vb;
            }
            __syncthreads();
            #pragma unroll
            for (int h4 = 0; h4 < BH / 4; h4++) {
                float4 a[TM], b[TN];
                #pragma unroll
                for (int i = 0; i < TM; i++) a[i] = *(const float4*)&As[tr + 16 * i][h4 * 4];
                #pragma unroll
                for (int j = 0; j < TN; j++) b[j] = *(const float4*)&Bs[tc + 16 * j][h4 * 4];
                #pragma unroll
                for (int i = 0; i < TM; i++)
                    #pragma unroll
                    for (int j = 0; j < TN; j++)
                        dot[i][j] += a[i].x * b[j].x + a[i].y * b[j].y
                                   + a[i].z * b[j].z + a[i].w * b[j].w;
            }
        }
        // distances + tracker update (j ascending => k ascending within thread)
        #pragma unroll
        for (int j = 0; j < TN; j++) {
            int col = tc + 16 * j;
            int k   = kbase + col;
            float c2v = c2s[col];
            #pragma unroll
            for (int i = 0; i < TM; i++) {
                float d = c2v - 2.f * dot[i][j];
                if (d < best[i])        { second[i] = best[i]; best[i] = d; bidx[i] = k; }
                else if (d < second[i]) { second[i] = d; }
            }
        }
    }

    // Epilogue: merge the 16 thread-columns per row via LDS (overlay on smem).
    __syncthreads();
    float* mbest   = smem;
    float* msecond = smem + BM * 16;
    int*   midx    = (int*)(smem + 2 * BM * 16);
    #pragma unroll
    for (int i = 0; i < TM; i++) {
        int r = tr + 16 * i;
        mbest[r * 16 + tc]   = best[i];
        msecond[r * 16 + tc] = second[i];
        midx[r * 16 + tc]    = bidx[i];
    }
    __syncthreads();
    if (tid < BM) {
        float b  = mbest[tid * 16];
        float s2 = msecond[tid * 16];
        int   bi = midx[tid * 16];
        for (int t = 1; t < 16; t++) {
            float ob = mbest[tid * 16 + t];
            float os = msecond[tid * 16 + t];
            int   oi = midx[tid * 16 + t];
            if (ob < b)       { s2 = fminf(b, os); b = ob; bi = oi; }
            else if (ob > b)  { s2 = fminf(s2, ob); }
            else              { if (oi < bi) bi = oi; s2 = b; }
        }
        int row = row0 + tid;
        int s   = blockIdx.y;
        ws[BESTP_OFF   + s * N_ROWS + row] = b;
        ws[SECONDP_OFF + s * N_ROWS + row] = s2;
        ((int*)ws)[IDXP_OFF + s * N_ROWS + row] = bi;
    }
}

// ---------------------------------------------------------------------------
// M: merge the 8 k-splits per row; emit full dist, argmin, and tie gap.
__global__ __launch_bounds__(256) void merge_kernel(float* __restrict__ ws) {
    int row = blockIdx.x * blockDim.x + threadIdx.x;
    if (row >= N_ROWS) return;
    float b  = ws[BESTP_OFF + row];
    float s2 = ws[SECONDP_OFF + row];
    int   bi = ((int*)ws)[IDXP_OFF + row];
    for (int s = 1; s < NSPLIT; s++) {
        float ob = ws[BESTP_OFF   + s * N_ROWS + row];
        float os = ws[SECONDP_OFF + s * N_ROWS + row];
        int   oi = ((int*)ws)[IDXP_OFF + s * N_ROWS + row];
        if (ob < b)      { s2 = fminf(b, os); b = ob; bi = oi; }
        else if (ob > b) { s2 = fminf(s2, ob); }
        else             { if (oi < bi) bi = oi; s2 = b; }
    }
    float h2 = ws[H2_OFF + row];
    ws[DISTF_OFF + row] = h2 + b;       // ||h - c||^2 at the argmin
    ((int*)ws)[IDXF_OFF + row] = bi;
    ws[GAP_OFF + row] = s2 - b;
}

// ---------------------------------------------------------------------------
// C: fp64 re-resolution for near-tie rows (gap <= MARGIN). One block per row;
// non-flagged blocks exit immediately.
__global__ __launch_bounds__(256) void fixup_kernel(const float* __restrict__ h,
                                                    const float* __restrict__ cb,
                                                    float* __restrict__ ws) {
    int row = blockIdx.x;
    if (ws[GAP_OFF + row] > MARGIN) return;

    __shared__ float hrow[H_DIM];
    __shared__ double sb[256];
    __shared__ int    si[256];
    int tid = threadIdx.x;
    hrow[tid] = h[(size_t)row * H_DIM + tid];
    __syncthreads();

    double bestd = 1e300;
    int    bi    = K_CODES;
    for (int k = tid; k < K_CODES; k += 256) {   // k ascending per thread
        const float* c = cb + (size_t)k * H_DIM;
        double acc = 0.0;
        for (int x = 0; x < H_DIM; x++) {
            double d = (double)hrow[x] - (double)c[x];
            acc += d * d;
        }
        if (acc < bestd) { bestd = acc; bi = k; }
    }
    sb[tid] = bestd; si[tid] = bi;
    __syncthreads();
    for (int off = 128; off > 0; off >>= 1) {
        if (tid < off) {
            double ob = sb[tid + off]; int oi = si[tid + off];
            if (ob < sb[tid] || (ob == sb[tid] && oi < si[tid])) { sb[tid] = ob; si[tid] = oi; }
        }
        __syncthreads();
    }
    if (tid == 0) {
        ws[DISTF_OFF + row] = (float)sb[0];
        ((int*)ws)[IDXF_OFF + row] = si[0];
    }
}

// ---------------------------------------------------------------------------
// B: write one-hot rows (float4 streaming stores) + loss.
__global__ __launch_bounds__(256) void writeout_kernel(const float* __restrict__ ws,
                                                       float* __restrict__ out) {
    int row = blockIdx.x;
    int tid = threadIdx.x;
    int bi  = ((const int*)ws)[IDXF_OFF + row];
    float4* orow = (float4*)(out + (size_t)row * K_CODES);
    #pragma unroll
    for (int i = 0; i < 8; i++) {
        int f4 = tid + 256 * i;            // 0..2047
        float4 v = make_float4(0.f, 0.f, 0.f, 0.f);
        if ((bi >> 2) == f4) ((float*)&v)[bi & 3] = 1.0f;
        orow[f4] = v;
    }
    if (tid == 0) {
        out[(size_t)N_ROWS * K_CODES + row] = (1.25f / 256.f) * ws[DISTF_OFF + row];
    }
}

// ---------------------------------------------------------------------------
extern "C" void kernel_launch(void* const* d_in, const int* in_sizes, int n_in,
                              void* d_out, int out_size, void* d_ws, size_t ws_size,
                              hipStream_t stream) {
    const float* h  = (const float*)d_in[0];
    // d_in[1] = temperature (unused)
    const float* cb = (const float*)d_in[2];
    float* out = (float*)d_out;
    float* ws  = (float*)d_ws;

    prep_sq<<<4096, 256, 0, stream>>>(h, cb, ws);
    vq_min_kernel<<<dim3(N_ROWS / BM, NSPLIT), 256, 0, stream>>>(h, cb, ws);
    merge_kernel<<<N_ROWS / 256, 256, 0, stream>>>(ws);
    fixup_kernel<<<N_ROWS, 256, 0, stream>>>(h, cb, ws);
    writeout_kernel<<<N_ROWS, 256, 0, stream>>>(ws, out);
}

// Round 3
// 1520.812 us; speedup vs baseline: 6.8152x; 2.6362x over previous
//
#include <hip/hip_runtime.h>
#include <hip/hip_bf16.h>
#include <math.h>

// Problem constants (fixed by the reference).
#define N_ROWS   8192
#define K_CODES  8192
#define H_DIM    256
#define NSPLIT   8
#define KSPLIT   (K_CODES / NSPLIT)   // 1024 codes per block (8 code-tiles of 128)
#define MARGIN   5e-4f                // bf16-split dot err ~2e-5; 20x safety

// MFMA GEMM-min tiling
#define BM 128                        // h rows per block
#define BN 128                        // codes per tile
#define BK 32                         // H chunk per stage (one MFMA K)
#define LDS_RSTR 40                   // shorts per LDS tile row (32 + 8 pad; 80B keeps 16B align, 2-way banks)

typedef short short8 __attribute__((ext_vector_type(8)));   // 8 bf16 = 4 VGPRs (MFMA A/B frag)
typedef float f32x4  __attribute__((ext_vector_type(4)));   // MFMA C/D frag

// Workspace layout (float offsets)
#define C2_OFF      0
#define H2_OFF      8192
#define BESTP_OFF   16384
#define SECONDP_OFF (BESTP_OFF + 8*8192)
#define IDXP_OFF    (SECONDP_OFF + 8*8192)
#define DISTF_OFF   (IDXP_OFF + 8*8192)
#define IDXF_OFF    (DISTF_OFF + 8192)
#define GAP_OFF     (IDXF_OFF + 8192)

// ---------------------------------------------------------------------------
__global__ __launch_bounds__(256) void prep_sq(const float* __restrict__ h,
                                               const float* __restrict__ cb,
                                               float* __restrict__ ws) {
    int blk  = blockIdx.x;
    int wave = threadIdx.x >> 6;
    int lane = threadIdx.x & 63;
    bool isH = blk >= 2048;
    int idx  = (isH ? (blk - 2048) : blk) * 4 + wave;
    const float* src = isH ? h : cb;
    const float4* p = (const float4*)(src + (size_t)idx * H_DIM);
    float4 v = p[lane];
    float s = v.x*v.x + v.y*v.y + v.z*v.z + v.w*v.w;
    #pragma unroll
    for (int off = 32; off > 0; off >>= 1) s += __shfl_down(s, off, 64);
    if (lane == 0) ws[(isH ? H2_OFF : C2_OFF) + idx] = s;
}

// ---------------------------------------------------------------------------
// fp32 -> bf16 hi/lo split, two elements at a time (RNE both; residual exact).
__device__ __forceinline__ void conv2(float a, float b, unsigned& hi, unsigned& lo) {
    float2 p0 = make_float2(a, b);
    __hip_bfloat162 hb = __float22bfloat162_rn(p0);
    unsigned h = *(unsigned*)&hb;
    hi = h;
    float ra = a - __uint_as_float(h << 16);
    float rb = b - __uint_as_float(h & 0xFFFF0000u);
    float2 p1 = make_float2(ra, rb);
    __hip_bfloat162 lb = __float22bfloat162_rn(p1);
    lo = *(unsigned*)&lb;
}

// Stage a 128x32 fp32 tile as hi/lo bf16 tiles in LDS (padded rows).
__device__ __forceinline__ void stage_tile(const float* __restrict__ src, int src_row0,
                                           int kc, char* hiT, char* loT, int tid) {
    #pragma unroll
    for (int p = 0; p < 2; ++p) {
        int idx = tid + p * 256;            // 0..511
        int r   = idx >> 2;                 // 0..127
        int oct = idx & 3;                  // k-octet
        const float* s = src + (size_t)(src_row0 + r) * H_DIM + kc * 32 + oct * 8;
        float4 v0 = *(const float4*)s;
        float4 v1 = *(const float4*)(s + 4);
        unsigned hi0, hi1, hi2, hi3, lo0, lo1, lo2, lo3;
        conv2(v0.x, v0.y, hi0, lo0);
        conv2(v0.z, v0.w, hi1, lo1);
        conv2(v1.x, v1.y, hi2, lo2);
        conv2(v1.z, v1.w, hi3, lo3);
        int boff = r * (LDS_RSTR * 2) + oct * 16;
        *(uint4*)(hiT + boff) = make_uint4(hi0, hi1, hi2, hi3);
        *(uint4*)(loT + boff) = make_uint4(lo0, lo1, lo2, lo3);
    }
}

// ---------------------------------------------------------------------------
// A: bf16-split MFMA GEMM-min. Block = (row-tile, k-split); 4 waves of 64x64.
// acc lives in AGPRs; tracker (best/second/idx per 16 rows) in VGPRs.
__global__ __launch_bounds__(256, 2) void vq_min_kernel(const float* __restrict__ h,
                                                        const float* __restrict__ cb,
                                                        float* __restrict__ ws) {
    __shared__ __align__(16) char smem[49152];   // tiles (40960) / merge overlay (49152)
    char* Ahi = smem;
    char* Alo = smem + 10240;
    char* Bhi = smem + 20480;
    char* Blo = smem + 30720;

    const int row0 = blockIdx.x * BM;
    const int k0   = blockIdx.y * KSPLIT;
    const int tid  = threadIdx.x;
    const int w    = tid >> 6;
    const int lane = tid & 63;
    const int ln15 = lane & 15;
    const int kg   = lane >> 4;          // 0..3
    const int wm   = (w >> 1) * 64;      // wave row offset
    const int wn   = (w & 1) * 64;       // wave col offset

    const float* c2g = ws + C2_OFF;

    float best16[16], sec16[16];
    int   idx16[16];
    #pragma unroll
    for (int t = 0; t < 16; t++) { best16[t] = 3.4e38f; sec16[t] = 3.4e38f; idx16[t] = 0; }

    #pragma unroll 1
    for (int ct = 0; ct < KSPLIT / BN; ++ct) {
        const int kb = k0 + ct * BN;
        f32x4 acc[4][4];
        #pragma unroll
        for (int i = 0; i < 4; i++)
            #pragma unroll
            for (int j = 0; j < 4; j++) acc[i][j] = (f32x4){0.f, 0.f, 0.f, 0.f};

        #pragma unroll 1
        for (int kc = 0; kc < H_DIM / BK; ++kc) {
            __syncthreads();
            stage_tile(h,  row0, kc, Ahi, Alo, tid);
            stage_tile(cb, kb,   kc, Bhi, Blo, tid);
            __syncthreads();

            short8 ah[4], al[4], bh[4], bl[4];
            #pragma unroll
            for (int i = 0; i < 4; i++) {
                int boff = (wm + i * 16 + ln15) * (LDS_RSTR * 2) + kg * 16;
                ah[i] = *(const short8*)(Ahi + boff);
                al[i] = *(const short8*)(Alo + boff);
            }
            #pragma unroll
            for (int j = 0; j < 4; j++) {
                int boff = (wn + j * 16 + ln15) * (LDS_RSTR * 2) + kg * 16;
                bh[j] = *(const short8*)(Bhi + boff);
                bl[j] = *(const short8*)(Blo + boff);
            }
            #pragma unroll
            for (int i = 0; i < 4; i++)
                #pragma unroll
                for (int j = 0; j < 4; j++) {
                    acc[i][j] = __builtin_amdgcn_mfma_f32_16x16x32_bf16(ah[i], bh[j], acc[i][j], 0, 0, 0);
                    acc[i][j] = __builtin_amdgcn_mfma_f32_16x16x32_bf16(al[i], bh[j], acc[i][j], 0, 0, 0);
                    acc[i][j] = __builtin_amdgcn_mfma_f32_16x16x32_bf16(ah[i], bl[j], acc[i][j], 0, 0, 0);
                }
        }

        // distances for this 128-code tile; update per-row trackers (k ascending in j)
        float cv[4];
        #pragma unroll
        for (int j = 0; j < 4; j++) cv[j] = c2g[kb + wn + j * 16 + ln15];
        #pragma unroll
        for (int i = 0; i < 4; i++)
            #pragma unroll
            for (int reg = 0; reg < 4; reg++) {
                const int t = i * 4 + reg;
                #pragma unroll
                for (int j = 0; j < 4; j++) {
                    float d = cv[j] - 2.f * acc[i][j][reg];
                    int   k = kb + wn + j * 16 + ln15;
                    if (d < best16[t])      { sec16[t] = best16[t]; best16[t] = d; idx16[t] = k; }
                    else if (d < sec16[t])  { sec16[t] = d; }
                }
            }
    }

    // Cross-lane merge: LDS overlay [row][32 slots] (2 col-waves x 16 lanes).
    __syncthreads();
    float* mb = (float*)smem;                 // 128*32
    float* ms = (float*)(smem + 16384);
    int*   mi = (int*)(smem + 32768);
    #pragma unroll
    for (int i = 0; i < 4; i++)
        #pragma unroll
        for (int reg = 0; reg < 4; reg++) {
            int r    = wm + i * 16 + kg * 4 + reg;
            int slot = (w & 1) * 16 + ln15;
            mb[r * 32 + slot] = best16[i * 4 + reg];
            ms[r * 32 + slot] = sec16[i * 4 + reg];
            mi[r * 32 + slot] = idx16[i * 4 + reg];
        }
    __syncthreads();
    if (tid < BM) {
        float b  = mb[tid * 32];
        float s2 = ms[tid * 32];
        int   bi = mi[tid * 32];
        for (int t = 1; t < 32; t++) {
            float ob = mb[tid * 32 + t];
            float os = ms[tid * 32 + t];
            int   oi = mi[tid * 32 + t];
            if (ob < b)       { s2 = fminf(b, os); b = ob; bi = oi; }
            else if (ob > b)  { s2 = fminf(s2, ob); }
            else              { if (oi < bi) bi = oi; s2 = b; }
        }
        int row = row0 + tid;
        int s   = blockIdx.y;
        ws[BESTP_OFF   + s * N_ROWS + row] = b;
        ws[SECONDP_OFF + s * N_ROWS + row] = s2;
        ((int*)ws)[IDXP_OFF + s * N_ROWS + row] = bi;
    }
}

// ---------------------------------------------------------------------------
__global__ __launch_bounds__(256) void merge_kernel(float* __restrict__ ws) {
    int row = blockIdx.x * blockDim.x + threadIdx.x;
    if (row >= N_ROWS) return;
    float b  = ws[BESTP_OFF + row];
    float s2 = ws[SECONDP_OFF + row];
    int   bi = ((int*)ws)[IDXP_OFF + row];
    for (int s = 1; s < NSPLIT; s++) {
        float ob = ws[BESTP_OFF   + s * N_ROWS + row];
        float os = ws[SECONDP_OFF + s * N_ROWS + row];
        int   oi = ((int*)ws)[IDXP_OFF + s * N_ROWS + row];
        if (ob < b)      { s2 = fminf(b, os); b = ob; bi = oi; }
        else if (ob > b) { s2 = fminf(s2, ob); }
        else             { if (oi < bi) bi = oi; s2 = b; }
    }
    float h2 = ws[H2_OFF + row];
    ws[DISTF_OFF + row] = h2 + b;
    ((int*)ws)[IDXF_OFF + row] = bi;
    ws[GAP_OFF + row] = s2 - b;
}

// ---------------------------------------------------------------------------
// C: fp64 re-resolution for near-tie rows. Coalesced: each wave scans codes
// (stride 4), 64 lanes x float4 = one full code row per load; fp64 accumulate.
__global__ __launch_bounds__(256) void fixup_kernel(const float* __restrict__ h,
                                                    const float* __restrict__ cb,
                                                    float* __restrict__ ws) {
    int row = blockIdx.x;
    if (ws[GAP_OFF + row] > MARGIN) return;

    int wv   = threadIdx.x >> 6;
    int lane = threadIdx.x & 63;
    float4 hv = *(const float4*)(h + (size_t)row * H_DIM + lane * 4);

    double best = 1e300;
    int    bi   = K_CODES;
    for (int c = wv; c < K_CODES; c += 4) {     // ascending per wave
        float4 cv = *(const float4*)(cb + (size_t)c * H_DIM + lane * 4);
        float dx = hv.x - cv.x, dy = hv.y - cv.y, dz = hv.z - cv.z, dw = hv.w - cv.w;
        double s = (double)dx * dx + (double)dy * dy + (double)dz * dz + (double)dw * dw;
        #pragma unroll
        for (int off = 32; off > 0; off >>= 1) s += __shfl_down(s, off, 64);
        if (lane == 0 && s < best) { best = s; bi = c; }
    }
    __shared__ double sb[4];
    __shared__ int    si[4];
    if (lane == 0) { sb[wv] = best; si[wv] = bi; }
    __syncthreads();
    if (threadIdx.x == 0) {
        double b = sb[0]; int x = si[0];
        for (int t = 1; t < 4; t++) {
            if (sb[t] < b || (sb[t] == b && si[t] < x)) { b = sb[t]; x = si[t]; }
        }
        ws[DISTF_OFF + row] = (float)b;
        ((int*)ws)[IDXF_OFF + row] = x;
    }
}

// ---------------------------------------------------------------------------
__global__ __launch_bounds__(256) void writeout_kernel(const float* __restrict__ ws,
                                                       float* __restrict__ out) {
    int row = blockIdx.x;
    int tid = threadIdx.x;
    int bi  = ((const int*)ws)[IDXF_OFF + row];
    float4* orow = (float4*)(out + (size_t)row * K_CODES);
    #pragma unroll
    for (int i = 0; i < 8; i++) {
        int f4 = tid + 256 * i;
        float4 v = make_float4(0.f, 0.f, 0.f, 0.f);
        if ((bi >> 2) == f4) ((float*)&v)[bi & 3] = 1.0f;
        orow[f4] = v;
    }
    if (tid == 0) {
        out[(size_t)N_ROWS * K_CODES + row] = (1.25f / 256.f) * ws[DISTF_OFF + row];
    }
}

// ---------------------------------------------------------------------------
extern "C" void kernel_launch(void* const* d_in, const int* in_sizes, int n_in,
                              void* d_out, int out_size, void* d_ws, size_t ws_size,
                              hipStream_t stream) {
    const float* h  = (const float*)d_in[0];
    const float* cb = (const float*)d_in[2];
    float* out = (float*)d_out;
    float* ws  = (float*)d_ws;

    prep_sq<<<4096, 256, 0, stream>>>(h, cb, ws);
    vq_min_kernel<<<dim3(N_ROWS / BM, NSPLIT), 256, 0, stream>>>(h, cb, ws);
    merge_kernel<<<N_ROWS / 256, 256, 0, stream>>>(ws);
    fixup_kernel<<<N_ROWS, 256, 0, stream>>>(h, cb, ws);
    writeout_kernel<<<N_ROWS, 256, 0, stream>>>(ws, out);
}

// Round 4
// 511.854 us; speedup vs baseline: 20.2492x; 2.9712x over previous
//
#include <hip/hip_runtime.h>
#include <hip/hip_bf16.h>
#include <math.h>

// Problem constants (fixed by the reference).
#define N_ROWS   8192
#define K_CODES  8192
#define H_DIM    256
#define NSPLIT   8
#define KSPLIT   (K_CODES / NSPLIT)   // 1024 codes per block (8 code-tiles of 128)
#define MARGIN   5e-4f                // bf16-split dot err ~2e-5; 20x safety

// MFMA GEMM-min tiling
#define BM 128
#define BN 128
#define BK 32
#define LDS_RSTR 40                   // shorts per LDS row (32 + 8 pad)

typedef short short8 __attribute__((ext_vector_type(8)));
typedef float f32x4  __attribute__((ext_vector_type(4)));

// Workspace layout (float offsets)
#define C2_OFF      0
#define H2_OFF      8192
#define BESTP_OFF   16384
#define SECONDP_OFF (BESTP_OFF + 8*8192)
#define IDXP_OFF    (SECONDP_OFF + 8*8192)
#define DISTF_OFF   (IDXP_OFF + 8*8192)
#define IDXF_OFF    (DISTF_OFF + 8192)
#define GAP_OFF     (IDXF_OFF + 8192)
// fixup compaction + partials (R4): ~3 rows expected flagged (FETCH evidence R3)
#define FCNT_OFF    245760                    // int counter
#define FLIST_OFF   245776                    // int[64] flagged row ids
#define PBEST_OFF   245840                    // double[64][64] (byte off 983360, 8-aligned)
#define PIDX_OFF    (PBEST_OFF + 8192)        // int[64*64]
#define MAXSLOT     64

// ---------------------------------------------------------------------------
__global__ __launch_bounds__(256) void prep_sq(const float* __restrict__ h,
                                               const float* __restrict__ cb,
                                               float* __restrict__ ws) {
    if (blockIdx.x == 0 && threadIdx.x == 0) ((int*)ws)[FCNT_OFF] = 0;
    int blk  = blockIdx.x;
    int wave = threadIdx.x >> 6;
    int lane = threadIdx.x & 63;
    bool isH = blk >= 2048;
    int idx  = (isH ? (blk - 2048) : blk) * 4 + wave;
    const float* src = isH ? h : cb;
    const float4* p = (const float4*)(src + (size_t)idx * H_DIM);
    float4 v = p[lane];
    float s = v.x*v.x + v.y*v.y + v.z*v.z + v.w*v.w;
    #pragma unroll
    for (int off = 32; off > 0; off >>= 1) s += __shfl_down(s, off, 64);
    if (lane == 0) ws[(isH ? H2_OFF : C2_OFF) + idx] = s;
}

// ---------------------------------------------------------------------------
__device__ __forceinline__ void conv2(float a, float b, unsigned& hi, unsigned& lo) {
    float2 p0 = make_float2(a, b);
    __hip_bfloat162 hb = __float22bfloat162_rn(p0);
    unsigned h = *(unsigned*)&hb;
    hi = h;
    float ra = a - __uint_as_float(h << 16);
    float rb = b - __uint_as_float(h & 0xFFFF0000u);
    float2 p1 = make_float2(ra, rb);
    __hip_bfloat162 lb = __float22bfloat162_rn(p1);
    lo = *(unsigned*)&lb;
}

__device__ __forceinline__ void stage_tile(const float* __restrict__ src, int src_row0,
                                           int kc, char* hiT, char* loT, int tid) {
    #pragma unroll
    for (int p = 0; p < 2; ++p) {
        int idx = tid + p * 256;
        int r   = idx >> 2;
        int oct = idx & 3;
        const float* s = src + (size_t)(src_row0 + r) * H_DIM + kc * 32 + oct * 8;
        float4 v0 = *(const float4*)s;
        float4 v1 = *(const float4*)(s + 4);
        unsigned hi0, hi1, hi2, hi3, lo0, lo1, lo2, lo3;
        conv2(v0.x, v0.y, hi0, lo0);
        conv2(v0.z, v0.w, hi1, lo1);
        conv2(v1.x, v1.y, hi2, lo2);
        conv2(v1.z, v1.w, hi3, lo3);
        int boff = r * (LDS_RSTR * 2) + oct * 16;
        *(uint4*)(hiT + boff) = make_uint4(hi0, hi1, hi2, hi3);
        *(uint4*)(loT + boff) = make_uint4(lo0, lo1, lo2, lo3);
    }
}

// ---------------------------------------------------------------------------
__global__ __launch_bounds__(256, 2) void vq_min_kernel(const float* __restrict__ h,
                                                        const float* __restrict__ cb,
                                                        float* __restrict__ ws) {
    __shared__ __align__(16) char smem[49152];
    char* Ahi = smem;
    char* Alo = smem + 10240;
    char* Bhi = smem + 20480;
    char* Blo = smem + 30720;

    const int row0 = blockIdx.x * BM;
    const int k0   = blockIdx.y * KSPLIT;
    const int tid  = threadIdx.x;
    const int w    = tid >> 6;
    const int lane = tid & 63;
    const int ln15 = lane & 15;
    const int kg   = lane >> 4;
    const int wm   = (w >> 1) * 64;
    const int wn   = (w & 1) * 64;

    const float* c2g = ws + C2_OFF;

    float best16[16], sec16[16];
    int   idx16[16];
    #pragma unroll
    for (int t = 0; t < 16; t++) { best16[t] = 3.4e38f; sec16[t] = 3.4e38f; idx16[t] = 0; }

    #pragma unroll 1
    for (int ct = 0; ct < KSPLIT / BN; ++ct) {
        const int kb = k0 + ct * BN;
        f32x4 acc[4][4];
        #pragma unroll
        for (int i = 0; i < 4; i++)
            #pragma unroll
            for (int j = 0; j < 4; j++) acc[i][j] = (f32x4){0.f, 0.f, 0.f, 0.f};

        #pragma unroll 1
        for (int kc = 0; kc < H_DIM / BK; ++kc) {
            __syncthreads();
            stage_tile(h,  row0, kc, Ahi, Alo, tid);
            stage_tile(cb, kb,   kc, Bhi, Blo, tid);
            __syncthreads();

            short8 ah[4], al[4], bh[4], bl[4];
            #pragma unroll
            for (int i = 0; i < 4; i++) {
                int boff = (wm + i * 16 + ln15) * (LDS_RSTR * 2) + kg * 16;
                ah[i] = *(const short8*)(Ahi + boff);
                al[i] = *(const short8*)(Alo + boff);
            }
            #pragma unroll
            for (int j = 0; j < 4; j++) {
                int boff = (wn + j * 16 + ln15) * (LDS_RSTR * 2) + kg * 16;
                bh[j] = *(const short8*)(Bhi + boff);
                bl[j] = *(const short8*)(Blo + boff);
            }
            #pragma unroll
            for (int i = 0; i < 4; i++)
                #pragma unroll
                for (int j = 0; j < 4; j++) {
                    acc[i][j] = __builtin_amdgcn_mfma_f32_16x16x32_bf16(ah[i], bh[j], acc[i][j], 0, 0, 0);
                    acc[i][j] = __builtin_amdgcn_mfma_f32_16x16x32_bf16(al[i], bh[j], acc[i][j], 0, 0, 0);
                    acc[i][j] = __builtin_amdgcn_mfma_f32_16x16x32_bf16(ah[i], bl[j], acc[i][j], 0, 0, 0);
                }
        }

        float cv[4];
        #pragma unroll
        for (int j = 0; j < 4; j++) cv[j] = c2g[kb + wn + j * 16 + ln15];
        #pragma unroll
        for (int i = 0; i < 4; i++)
            #pragma unroll
            for (int reg = 0; reg < 4; reg++) {
                const int t = i * 4 + reg;
                #pragma unroll
                for (int j = 0; j < 4; j++) {
                    float d = cv[j] - 2.f * acc[i][j][reg];
                    int   k = kb + wn + j * 16 + ln15;
                    if (d < best16[t])      { sec16[t] = best16[t]; best16[t] = d; idx16[t] = k; }
                    else if (d < sec16[t])  { sec16[t] = d; }
                }
            }
    }

    __syncthreads();
    float* mb = (float*)smem;
    float* ms = (float*)(smem + 16384);
    int*   mi = (int*)(smem + 32768);
    #pragma unroll
    for (int i = 0; i < 4; i++)
        #pragma unroll
        for (int reg = 0; reg < 4; reg++) {
            int r    = wm + i * 16 + kg * 4 + reg;
            int slot = (w & 1) * 16 + ln15;
            mb[r * 32 + slot] = best16[i * 4 + reg];
            ms[r * 32 + slot] = sec16[i * 4 + reg];
            mi[r * 32 + slot] = idx16[i * 4 + reg];
        }
    __syncthreads();
    if (tid < BM) {
        float b  = mb[tid * 32];
        float s2 = ms[tid * 32];
        int   bi = mi[tid * 32];
        for (int t = 1; t < 32; t++) {
            float ob = mb[tid * 32 + t];
            float os = ms[tid * 32 + t];
            int   oi = mi[tid * 32 + t];
            if (ob < b)       { s2 = fminf(b, os); b = ob; bi = oi; }
            else if (ob > b)  { s2 = fminf(s2, ob); }
            else              { if (oi < bi) bi = oi; s2 = b; }
        }
        int row = row0 + tid;
        int s   = blockIdx.y;
        ws[BESTP_OFF   + s * N_ROWS + row] = b;
        ws[SECONDP_OFF + s * N_ROWS + row] = s2;
        ((int*)ws)[IDXP_OFF + s * N_ROWS + row] = bi;
    }
}

// ---------------------------------------------------------------------------
// M: merge k-splits; flag near-tie rows into a compact list for parallel fixup.
__global__ __launch_bounds__(256) void merge_kernel(float* __restrict__ ws) {
    int row = blockIdx.x * blockDim.x + threadIdx.x;
    if (row >= N_ROWS) return;
    float b  = ws[BESTP_OFF + row];
    float s2 = ws[SECONDP_OFF + row];
    int   bi = ((int*)ws)[IDXP_OFF + row];
    for (int s = 1; s < NSPLIT; s++) {
        float ob = ws[BESTP_OFF   + s * N_ROWS + row];
        float os = ws[SECONDP_OFF + s * N_ROWS + row];
        int   oi = ((int*)ws)[IDXP_OFF + s * N_ROWS + row];
        if (ob < b)      { s2 = fminf(b, os); b = ob; bi = oi; }
        else if (ob > b) { s2 = fminf(s2, ob); }
        else             { if (oi < bi) bi = oi; s2 = b; }
    }
    float h2 = ws[H2_OFF + row];
    ws[DISTF_OFF + row] = h2 + b;
    ((int*)ws)[IDXF_OFF + row] = bi;
    if (s2 - b <= MARGIN) {
        int slot = atomicAdd(&((int*)ws)[FCNT_OFF], 1);
        if (slot < MAXSLOT) ((int*)ws)[FLIST_OFF + slot] = row;
    }
}

// ---------------------------------------------------------------------------
// C1: per-(chunk, flagged-row) fp64 partial scan. 64 chunks x 128 codes.
__global__ __launch_bounds__(256) void fixup_part(const float* __restrict__ h,
                                                  const float* __restrict__ cb,
                                                  float* __restrict__ ws) {
    int slot = blockIdx.y;
    int n = ((const int*)ws)[FCNT_OFF];
    if (n > MAXSLOT) n = MAXSLOT;
    if (slot >= n) return;
    int row   = ((const int*)ws)[FLIST_OFF + slot];
    int base  = blockIdx.x * 128;
    int wv    = threadIdx.x >> 6;
    int lane  = threadIdx.x & 63;
    float4 hv = *(const float4*)(h + (size_t)row * H_DIM + lane * 4);

    double best = 1e300;
    int    bi   = 1 << 30;
    for (int c = base + wv; c < base + 128; c += 4) {   // ascending per wave
        float4 cv = *(const float4*)(cb + (size_t)c * H_DIM + lane * 4);
        float dx = hv.x - cv.x, dy = hv.y - cv.y, dz = hv.z - cv.z, dw = hv.w - cv.w;
        double s = (double)dx * dx + (double)dy * dy + (double)dz * dz + (double)dw * dw;
        #pragma unroll
        for (int off = 32; off > 0; off >>= 1) s += __shfl_down(s, off, 64);
        if (lane == 0 && s < best) { best = s; bi = c; }
    }
    __shared__ double sb[4];
    __shared__ int    si[4];
    if (lane == 0) { sb[wv] = best; si[wv] = bi; }
    __syncthreads();
    if (threadIdx.x == 0) {
        double b = sb[0]; int x = si[0];
        for (int t = 1; t < 4; t++)
            if (sb[t] < b || (sb[t] == b && si[t] < x)) { b = sb[t]; x = si[t]; }
        ((double*)(ws + PBEST_OFF))[slot * 64 + blockIdx.x] = b;
        ((int*)ws)[PIDX_OFF + slot * 64 + blockIdx.x] = x;
    }
}

// C2: one wave per flagged row reduces 64 chunk-partials (idx tie-break).
__global__ __launch_bounds__(64) void fixup_final(float* __restrict__ ws) {
    int slot = blockIdx.x;
    int n = ((const int*)ws)[FCNT_OFF];
    if (n > MAXSLOT) n = MAXSLOT;
    if (slot >= n) return;
    int lane = threadIdx.x;
    double b = ((const double*)(ws + PBEST_OFF))[slot * 64 + lane];
    int    x = ((const int*)ws)[PIDX_OFF + slot * 64 + lane];
    #pragma unroll
    for (int off = 32; off > 0; off >>= 1) {
        double ob = __shfl_down(b, off, 64);
        int    oi = __shfl_down(x, off, 64);
        if (ob < b || (ob == b && oi < x)) { b = ob; x = oi; }
    }
    if (lane == 0) {
        int row = ((const int*)ws)[FLIST_OFF + slot];
        ws[DISTF_OFF + row] = (float)b;
        ((int*)ws)[IDXF_OFF + row] = x;
    }
}

// ---------------------------------------------------------------------------
__global__ __launch_bounds__(256) void writeout_kernel(const float* __restrict__ ws,
                                                       float* __restrict__ out) {
    int row = blockIdx.x;
    int tid = threadIdx.x;
    int bi  = ((const int*)ws)[IDXF_OFF + row];
    float4* orow = (float4*)(out + (size_t)row * K_CODES);
    #pragma unroll
    for (int i = 0; i < 8; i++) {
        int f4 = tid + 256 * i;
        float4 v = make_float4(0.f, 0.f, 0.f, 0.f);
        if ((bi >> 2) == f4) ((float*)&v)[bi & 3] = 1.0f;
        orow[f4] = v;
    }
    if (tid == 0) {
        out[(size_t)N_ROWS * K_CODES + row] = (1.25f / 256.f) * ws[DISTF_OFF + row];
    }
}

// ---------------------------------------------------------------------------
extern "C" void kernel_launch(void* const* d_in, const int* in_sizes, int n_in,
                              void* d_out, int out_size, void* d_ws, size_t ws_size,
                              hipStream_t stream) {
    const float* h  = (const float*)d_in[0];
    const float* cb = (const float*)d_in[2];
    float* out = (float*)d_out;
    float* ws  = (float*)d_ws;

    prep_sq<<<4096, 256, 0, stream>>>(h, cb, ws);
    vq_min_kernel<<<dim3(N_ROWS / BM, NSPLIT), 256, 0, stream>>>(h, cb, ws);
    merge_kernel<<<N_ROWS / 256, 256, 0, stream>>>(ws);
    fixup_part<<<dim3(64, MAXSLOT), 256, 0, stream>>>(h, cb, ws);
    fixup_final<<<MAXSLOT, 64, 0, stream>>>(ws);
    writeout_kernel<<<N_ROWS, 256, 0, stream>>>(ws, out);
}

// Round 5
// 469.925 us; speedup vs baseline: 22.0559x; 1.0892x over previous
//
#include <hip/hip_runtime.h>
#include <hip/hip_bf16.h>
#include <math.h>

// Problem constants (fixed by the reference).
#define N_ROWS   8192
#define K_CODES  8192
#define H_DIM    256
#define NSPLIT   8
#define KSPLIT   (K_CODES / NSPLIT)   // 1024 codes per block-column (8 tiles of 128)
#define MARGIN   5e-4f                // bf16-split dot err ~2e-5; 20x safety

typedef short short8 __attribute__((ext_vector_type(8)));
typedef float f32x4  __attribute__((ext_vector_type(4)));

// Workspace layout (float offsets) — ~1 MB total, same as R4.
#define C2_OFF      0
#define H2_OFF      8192
#define BESTP_OFF   16384
#define SECONDP_OFF (BESTP_OFF + 8*8192)
#define IDXP_OFF    (SECONDP_OFF + 8*8192)
#define DISTF_OFF   (IDXP_OFF + 8*8192)
#define IDXF_OFF    (DISTF_OFF + 8192)
#define GAP_OFF     (IDXF_OFF + 8192)
#define FCNT_OFF    245760
#define FLIST_OFF   245776
#define PBEST_OFF   245840
#define PIDX_OFF    (PBEST_OFF + 8192)
#define MAXSLOT     64

// Packed bf16 hi/lo arrays live in the FIRST 16 MB of d_out (256 MB) as scratch.
// Safe: pack -> vq_min (reads) -> ... -> writeout (fully overwrites d_out). Stream-ordered.
// Layout: per (panel p of 16 rows, chunk c of 32 k): 64 lanes x 16 B, lane=(kg<<4)|ln15
// holds row p*16+ln15, k = c*32+kg*8..+7. Segment address = ((p*8+c)*64+lane)*16 bytes.
#define PK_AHI ((size_t)0)
#define PK_ALO ((size_t)4 << 20)
#define PK_BHI ((size_t)8 << 20)
#define PK_BLO ((size_t)12 << 20)

// ---------------------------------------------------------------------------
__device__ __forceinline__ void async_copy16(const void* g, void* l) {
    __builtin_amdgcn_global_load_lds(
        (const __attribute__((address_space(1))) unsigned int*)g,
        (__attribute__((address_space(3))) unsigned int*)l, 16, 0, 0);
}

// fp32 -> bf16 hi/lo split, two elements at a time (RNE both; residual exact).
__device__ __forceinline__ void conv2(float a, float b, unsigned& hi, unsigned& lo) {
    float2 p0 = make_float2(a, b);
    __hip_bfloat162 hb = __float22bfloat162_rn(p0);
    unsigned h = *(unsigned*)&hb;
    hi = h;
    float ra = a - __uint_as_float(h << 16);
    float rb = b - __uint_as_float(h & 0xFFFF0000u);
    float2 p1 = make_float2(ra, rb);
    __hip_bfloat162 lb = __float22bfloat162_rn(p1);
    lo = *(unsigned*)&lb;
}

// ---------------------------------------------------------------------------
__global__ __launch_bounds__(256) void prep_sq(const float* __restrict__ h,
                                               const float* __restrict__ cb,
                                               float* __restrict__ ws) {
    if (blockIdx.x == 0 && threadIdx.x == 0) ((int*)ws)[FCNT_OFF] = 0;
    int blk  = blockIdx.x;
    int wave = threadIdx.x >> 6;
    int lane = threadIdx.x & 63;
    bool isH = blk >= 2048;
    int idx  = (isH ? (blk - 2048) : blk) * 4 + wave;
    const float* src = isH ? h : cb;
    const float4* p = (const float4*)(src + (size_t)idx * H_DIM);
    float4 v = p[lane];
    float s = v.x*v.x + v.y*v.y + v.z*v.z + v.w*v.w;
    #pragma unroll
    for (int off = 32; off > 0; off >>= 1) s += __shfl_down(s, off, 64);
    if (lane == 0) ws[(isH ? H2_OFF : C2_OFF) + idx] = s;
}

// ---------------------------------------------------------------------------
// Pack h and cb into hi/lo bf16 fragment-order arrays. One (panel,chunk) per wave.
__global__ __launch_bounds__(256) void pack_kernel(const float* __restrict__ h,
                                                   const float* __restrict__ cb,
                                                   char* __restrict__ out) {
    int w    = threadIdx.x >> 6;
    int lane = threadIdx.x & 63;
    int ln15 = lane & 15;
    int kg   = lane >> 4;
    bool isB = blockIdx.x >= 1024;
    int u = ((blockIdx.x & 1023) << 2) + w;      // 0..4095 (panel*8 + chunk)
    int p = u >> 3, c = u & 7;
    const float* src = isB ? cb : h;
    char* hiB = out + (isB ? PK_BHI : PK_AHI);
    char* loB = out + (isB ? PK_BLO : PK_ALO);
    const float* s = src + (size_t)(p * 16 + ln15) * H_DIM + c * 32 + kg * 8;
    float4 v0 = *(const float4*)s;
    float4 v1 = *(const float4*)(s + 4);
    unsigned h0, h1, h2, h3, l0, l1, l2, l3;
    conv2(v0.x, v0.y, h0, l0);
    conv2(v0.z, v0.w, h1, l1);
    conv2(v1.x, v1.y, h2, l2);
    conv2(v1.z, v1.w, h3, l3);
    size_t off = ((size_t)u * 64 + lane) * 16;
    *(uint4*)(hiB + off) = make_uint4(h0, h1, h2, h3);
    *(uint4*)(loB + off) = make_uint4(l0, l1, l2, l3);
}

// ---------------------------------------------------------------------------
// A: bf16-split MFMA GEMM-min reading packed fragments.
// Staging: wave w stages its role (A-hi/A-lo/B-hi/B-lo), 8 x global_load_lds(16B).
// LDS: 4 regions x 8 KB (conflict-free lane*16 reads) + 3 KB merge = 35 KB.
__global__ __launch_bounds__(256, 2) void vq_min_kernel(const char* __restrict__ pk,
                                                        float* __restrict__ ws) {
    __shared__ __align__(16) char smem[35840];
    const int tid  = threadIdx.x;
    const int w    = tid >> 6;
    const int lane = tid & 63;
    const int ln15 = lane & 15;
    const int kg   = lane >> 4;
    const int wm   = (w >> 1) * 64;      // wave row offset
    const int wn   = (w & 1) * 64;       // wave col offset
    const int am   = (w >> 1) * 4;       // local A panel base
    const int bn4  = (w & 1) * 4;        // local B panel base

    const int rowpan0 = blockIdx.x * 8;  // global A panel base (8 panels = 128 rows)
    const int bpan0   = blockIdx.y * 64; // global B panel base for this split
    const float* c2g = ws + C2_OFF;

    const size_t pkoff = (w == 0) ? PK_AHI : (w == 1) ? PK_ALO : (w == 2) ? PK_BHI : PK_BLO;
    char* lwave = smem + w * 8192;

    float best16[16], sec16[16];
    int   idx16[16];
    #pragma unroll
    for (int t = 0; t < 16; t++) { best16[t] = 3.4e38f; sec16[t] = 3.4e38f; idx16[t] = 0; }

    #pragma unroll 1
    for (int ct = 0; ct < 8; ++ct) {
        const int kb   = blockIdx.y * KSPLIT + ct * 128;
        const int pan0 = (w < 2) ? rowpan0 : (bpan0 + ct * 8);
        f32x4 acc[4][4];
        #pragma unroll
        for (int i = 0; i < 4; i++)
            #pragma unroll
            for (int j = 0; j < 4; j++) acc[i][j] = (f32x4){0.f, 0.f, 0.f, 0.f};

        #pragma unroll 1
        for (int kc = 0; kc < 8; ++kc) {
            __syncthreads();                     // prior readers done before overwrite
            #pragma unroll
            for (int q = 0; q < 8; ++q) {
                const char* g = pk + pkoff + (((size_t)(pan0 + q) * 8 + kc) * 64 + lane) * 16;
                async_copy16(g, lwave + q * 1024);
            }
            __syncthreads();                     // drains vmcnt for global_load_lds

            short8 ah[4], al[4], bh[4], bl[4];
            #pragma unroll
            for (int i = 0; i < 4; i++) {
                int o = ((am + i) * 64 + lane) * 16;
                ah[i] = *(const short8*)(smem + o);
                al[i] = *(const short8*)(smem + 8192 + o);
            }
            #pragma unroll
            for (int j = 0; j < 4; j++) {
                int o = ((bn4 + j) * 64 + lane) * 16;
                bh[j] = *(const short8*)(smem + 16384 + o);
                bl[j] = *(const short8*)(smem + 24576 + o);
            }
            #pragma unroll
            for (int i = 0; i < 4; i++)
                #pragma unroll
                for (int j = 0; j < 4; j++) {
                    acc[i][j] = __builtin_amdgcn_mfma_f32_16x16x32_bf16(ah[i], bh[j], acc[i][j], 0, 0, 0);
                    acc[i][j] = __builtin_amdgcn_mfma_f32_16x16x32_bf16(al[i], bh[j], acc[i][j], 0, 0, 0);
                    acc[i][j] = __builtin_amdgcn_mfma_f32_16x16x32_bf16(ah[i], bl[j], acc[i][j], 0, 0, 0);
                }
        }

        // distances + tracker update (k strictly ascending within a lane)
        float cv[4];
        #pragma unroll
        for (int j = 0; j < 4; j++) cv[j] = c2g[kb + wn + j * 16 + ln15];
        #pragma unroll
        for (int i = 0; i < 4; i++)
            #pragma unroll
            for (int reg = 0; reg < 4; reg++) {
                const int t = i * 4 + reg;
                #pragma unroll
                for (int j = 0; j < 4; j++) {
                    float d = cv[j] - 2.f * acc[i][j][reg];
                    int   k = kb + wn + j * 16 + ln15;
                    if (d < best16[t])      { sec16[t] = best16[t]; best16[t] = d; idx16[t] = k; }
                    else if (d < sec16[t])  { sec16[t] = d; }
                }
            }
    }

    // Cross-lane merge over ln15 (butterfly within each 16-lane kg group).
    #pragma unroll
    for (int t = 0; t < 16; t++) {
        float b = best16[t], s2 = sec16[t];
        int   bi = idx16[t];
        #pragma unroll
        for (int m = 1; m <= 8; m <<= 1) {
            float ob = __shfl_xor(b, m, 64);
            float os = __shfl_xor(s2, m, 64);
            int   oi = __shfl_xor(bi, m, 64);
            if (ob < b)      { s2 = fminf(b, os); b = ob; bi = oi; }
            else if (ob > b) { s2 = fminf(s2, ob); }
            else             { if (oi < bi) bi = oi; s2 = b; }
        }
        best16[t] = b; sec16[t] = s2; idx16[t] = bi;
    }
    // Two column-halves per row -> small LDS merge region (above staging).
    float* mb = (float*)(smem + 32768);
    float* ms = (float*)(smem + 32768 + 1024);
    int*   mi = (int*)(smem + 32768 + 2048);
    if (ln15 == 0) {
        #pragma unroll
        for (int i = 0; i < 4; i++)
            #pragma unroll
            for (int reg = 0; reg < 4; reg++) {
                int r = wm + i * 16 + kg * 4 + reg;
                int half = (w & 1);
                mb[r * 2 + half] = best16[i * 4 + reg];
                ms[r * 2 + half] = sec16[i * 4 + reg];
                mi[r * 2 + half] = idx16[i * 4 + reg];
            }
    }
    __syncthreads();
    if (tid < 128) {
        float b  = mb[tid * 2],     s2 = ms[tid * 2];
        int   bi = mi[tid * 2];
        float ob = mb[tid * 2 + 1], os = ms[tid * 2 + 1];
        int   oi = mi[tid * 2 + 1];
        if (ob < b)      { s2 = fminf(b, os); b = ob; bi = oi; }
        else if (ob > b) { s2 = fminf(s2, ob); }
        else             { if (oi < bi) bi = oi; s2 = b; }
        int row = blockIdx.x * 128 + tid;
        int s   = blockIdx.y;
        ws[BESTP_OFF   + s * N_ROWS + row] = b;
        ws[SECONDP_OFF + s * N_ROWS + row] = s2;
        ((int*)ws)[IDXP_OFF + s * N_ROWS + row] = bi;
    }
}

// ---------------------------------------------------------------------------
__global__ __launch_bounds__(256) void merge_kernel(float* __restrict__ ws) {
    int row = blockIdx.x * blockDim.x + threadIdx.x;
    if (row >= N_ROWS) return;
    float b  = ws[BESTP_OFF + row];
    float s2 = ws[SECONDP_OFF + row];
    int   bi = ((int*)ws)[IDXP_OFF + row];
    for (int s = 1; s < NSPLIT; s++) {
        float ob = ws[BESTP_OFF   + s * N_ROWS + row];
        float os = ws[SECONDP_OFF + s * N_ROWS + row];
        int   oi = ((int*)ws)[IDXP_OFF + s * N_ROWS + row];
        if (ob < b)      { s2 = fminf(b, os); b = ob; bi = oi; }
        else if (ob > b) { s2 = fminf(s2, ob); }
        else             { if (oi < bi) bi = oi; s2 = b; }
    }
    float h2 = ws[H2_OFF + row];
    ws[DISTF_OFF + row] = h2 + b;
    ((int*)ws)[IDXF_OFF + row] = bi;
    if (s2 - b <= MARGIN) {
        int slot = atomicAdd(&((int*)ws)[FCNT_OFF], 1);
        if (slot < MAXSLOT) ((int*)ws)[FLIST_OFF + slot] = row;
    }
}

// ---------------------------------------------------------------------------
__global__ __launch_bounds__(256) void fixup_part(const float* __restrict__ h,
                                                  const float* __restrict__ cb,
                                                  float* __restrict__ ws) {
    int slot = blockIdx.y;
    int n = ((const int*)ws)[FCNT_OFF];
    if (n > MAXSLOT) n = MAXSLOT;
    if (slot >= n) return;
    int row   = ((const int*)ws)[FLIST_OFF + slot];
    int base  = blockIdx.x * 128;
    int wv    = threadIdx.x >> 6;
    int lane  = threadIdx.x & 63;
    float4 hv = *(const float4*)(h + (size_t)row * H_DIM + lane * 4);

    double best = 1e300;
    int    bi   = 1 << 30;
    for (int c = base + wv; c < base + 128; c += 4) {
        float4 cv = *(const float4*)(cb + (size_t)c * H_DIM + lane * 4);
        float dx = hv.x - cv.x, dy = hv.y - cv.y, dz = hv.z - cv.z, dw = hv.w - cv.w;
        double s = (double)dx * dx + (double)dy * dy + (double)dz * dz + (double)dw * dw;
        #pragma unroll
        for (int off = 32; off > 0; off >>= 1) s += __shfl_down(s, off, 64);
        if (lane == 0 && s < best) { best = s; bi = c; }
    }
    __shared__ double sb[4];
    __shared__ int    si[4];
    if (lane == 0) { sb[wv] = best; si[wv] = bi; }
    __syncthreads();
    if (threadIdx.x == 0) {
        double b = sb[0]; int x = si[0];
        for (int t = 1; t < 4; t++)
            if (sb[t] < b || (sb[t] == b && si[t] < x)) { b = sb[t]; x = si[t]; }
        ((double*)(ws + PBEST_OFF))[slot * 64 + blockIdx.x] = b;
        ((int*)ws)[PIDX_OFF + slot * 64 + blockIdx.x] = x;
    }
}

__global__ __launch_bounds__(64) void fixup_final(float* __restrict__ ws) {
    int slot = blockIdx.x;
    int n = ((const int*)ws)[FCNT_OFF];
    if (n > MAXSLOT) n = MAXSLOT;
    if (slot >= n) return;
    int lane = threadIdx.x;
    double b = ((const double*)(ws + PBEST_OFF))[slot * 64 + lane];
    int    x = ((const int*)ws)[PIDX_OFF + slot * 64 + lane];
    #pragma unroll
    for (int off = 32; off > 0; off >>= 1) {
        double ob = __shfl_down(b, off, 64);
        int    oi = __shfl_down(x, off, 64);
        if (ob < b || (ob == b && oi < x)) { b = ob; x = oi; }
    }
    if (lane == 0) {
        int row = ((const int*)ws)[FLIST_OFF + slot];
        ws[DISTF_OFF + row] = (float)b;
        ((int*)ws)[IDXF_OFF + row] = x;
    }
}

// ---------------------------------------------------------------------------
__global__ __launch_bounds__(256) void writeout_kernel(const float* __restrict__ ws,
                                                       float* __restrict__ out) {
    int row = blockIdx.x;
    int tid = threadIdx.x;
    int bi  = ((const int*)ws)[IDXF_OFF + row];
    float4* orow = (float4*)(out + (size_t)row * K_CODES);
    #pragma unroll
    for (int i = 0; i < 8; i++) {
        int f4 = tid + 256 * i;
        float4 v = make_float4(0.f, 0.f, 0.f, 0.f);
        if ((bi >> 2) == f4) ((float*)&v)[bi & 3] = 1.0f;
        orow[f4] = v;
    }
    if (tid == 0) {
        out[(size_t)N_ROWS * K_CODES + row] = (1.25f / 256.f) * ws[DISTF_OFF + row];
    }
}

// ---------------------------------------------------------------------------
extern "C" void kernel_launch(void* const* d_in, const int* in_sizes, int n_in,
                              void* d_out, int out_size, void* d_ws, size_t ws_size,
                              hipStream_t stream) {
    const float* h  = (const float*)d_in[0];
    const float* cb = (const float*)d_in[2];
    float* out = (float*)d_out;
    float* ws  = (float*)d_ws;

    prep_sq<<<4096, 256, 0, stream>>>(h, cb, ws);
    pack_kernel<<<2048, 256, 0, stream>>>(h, cb, (char*)d_out);
    vq_min_kernel<<<dim3(N_ROWS / 128, NSPLIT), 256, 0, stream>>>((const char*)d_out, ws);
    merge_kernel<<<N_ROWS / 256, 256, 0, stream>>>(ws);
    fixup_part<<<dim3(64, MAXSLOT), 256, 0, stream>>>(h, cb, ws);
    fixup_final<<<MAXSLOT, 64, 0, stream>>>(ws);
    writeout_kernel<<<N_ROWS, 256, 0, stream>>>(ws, out);
}